// Round 1
// baseline (294.836 us; speedup 1.0000x reference)
//
#include <hip/hip_runtime.h>
#include <hip/hip_bf16.h>

// Problem constants (B,C,D,H,W = 2,64,16,16,16)
#define NB 2
#define NC 64
#define NS 4096   // D*H*W
#define GROUPS 32

typedef __attribute__((ext_vector_type(8))) short bf16x8;
typedef __attribute__((ext_vector_type(4))) short bf16x4;
typedef __attribute__((ext_vector_type(4))) float f32x4;

static __device__ __forceinline__ short f2bf(float f) {
    union { float f; unsigned u; } c; c.f = f;
    unsigned r = (c.u + 0x7FFFu + ((c.u >> 16) & 1u)) >> 16;  // RNE
    return (short)r;
}

// ---------------------------------------------------------------------------
// Kernel 1: QKV projection.  x:[B][C][N] f32 -> qT,kT:[B][N][C] bf16, vN:[B][C][N] bf16
// Block: 256 thr = 64 positions x 4 output-channel groups (16 ch each).
// ---------------------------------------------------------------------------
__global__ __launch_bounds__(256) void qkv_proj(
    const float* __restrict__ x,
    const float* __restrict__ Wq, const float* __restrict__ bq,
    const float* __restrict__ Wk, const float* __restrict__ bk,
    const float* __restrict__ Wv, const float* __restrict__ bv,
    short* __restrict__ qT, short* __restrict__ kT, short* __restrict__ vN)
{
    int t  = threadIdx.x;
    int nl = t & 63;
    int og = __builtin_amdgcn_readfirstlane(t >> 6);   // wave-uniform -> scalar W loads
    int pos = blockIdx.x * 64 + nl;
    int b = pos >> 12;
    int n = pos & (NS - 1);

    float aq[16], ak[16], av[16];
    #pragma unroll
    for (int o = 0; o < 16; ++o) {
        aq[o] = bq[og * 16 + o];
        ak[o] = bk[og * 16 + o];
        av[o] = bv[og * 16 + o];
    }
    const float* xb = x + (size_t)b * NC * NS + n;
    #pragma unroll 4
    for (int c = 0; c < NC; ++c) {
        float xv = xb[(size_t)c * NS];
        #pragma unroll
        for (int o = 0; o < 16; ++o) {
            int row = (og * 16 + o) * NC + c;
            aq[o] = fmaf(Wq[row], xv, aq[o]);
            ak[o] = fmaf(Wk[row], xv, ak[o]);
            av[o] = fmaf(Wv[row], xv, av[o]);
        }
    }
    // qT/kT rows: [b][n][c], 16 contiguous bf16 per thread
    size_t rowbase = ((size_t)b * NS + n) * NC + og * 16;
    union U8 { bf16x8 v; short s[8]; };
    U8 q0, q1, k0, k1;
    #pragma unroll
    for (int o = 0; o < 8; ++o) {
        q0.s[o] = f2bf(aq[o]);     q1.s[o] = f2bf(aq[8 + o]);
        k0.s[o] = f2bf(ak[o]);     k1.s[o] = f2bf(ak[8 + o]);
    }
    *(bf16x8*)(qT + rowbase)     = q0.v;
    *(bf16x8*)(qT + rowbase + 8) = q1.v;
    *(bf16x8*)(kT + rowbase)     = k0.v;
    *(bf16x8*)(kT + rowbase + 8) = k1.v;
    // vN: [b][c][n]
    #pragma unroll
    for (int o = 0; o < 16; ++o)
        vN[((size_t)b * NC + og * 16 + o) * NS + n] = f2bf(av[o]);
}

// ---------------------------------------------------------------------------
// Kernel 2: flash attention. One wave owns a 16-row Q tile; loops j in tiles of 64.
// S^T = mfma(A=K, B=Q): lane owns query col i = i0+(lane&15); rows j = 4*(lane>>4)+reg.
// PV:  O^T = mfma(A=V^T, B=P^T) with slot map j = 4g + (s&3) + 16*(s>>2) (+32*kc),
//      which is exactly the C/D row layout of S^T -> zero-shuffle P repack.
// h out: [B][C][N] f32
// ---------------------------------------------------------------------------
__global__ __launch_bounds__(256) void flash_attn(
    const short* __restrict__ qT, const short* __restrict__ kT,
    const short* __restrict__ vN, float* __restrict__ h)
{
    int t = threadIdx.x;
    int wid  = t >> 6;
    int lane = t & 63;
    int r = lane & 15;      // query index within tile (col of S^T)
    int g = lane >> 4;      // lane group
    int tile = blockIdx.x * 4 + wid;     // 0..511
    int b  = tile >> 8;
    int i0 = (tile & 255) * 16;

    const short* qb = qT + (size_t)b * NS * NC;
    const short* kb = kT + (size_t)b * NS * NC;
    const short* vb = vN + (size_t)b * NC * NS;

    // Q fragments (held all loop): B-operand, col = i0+r, k-slots c = 8g+s (+32)
    const bf16x8* qrow = (const bf16x8*)(qb + (size_t)(i0 + r) * NC);
    bf16x8 qf0 = qrow[g];
    bf16x8 qf1 = qrow[4 + g];

    f32x4 o_acc[4];
    #pragma unroll
    for (int cc = 0; cc < 4; ++cc) o_acc[cc] = (f32x4){0.f, 0.f, 0.f, 0.f};
    float m_run = -__builtin_inff();
    float l_run = 0.f;

    for (int j0 = 0; j0 < NS; j0 += 64) {
        // ---- S^T tiles: 4 j-chunks of 16 rows
        f32x4 s[4];
        #pragma unroll
        for (int jj = 0; jj < 4; ++jj) {
            const bf16x8* krow = (const bf16x8*)(kb + (size_t)(j0 + jj * 16 + r) * NC);
            f32x4 acc = (f32x4){0.f, 0.f, 0.f, 0.f};
            acc = __builtin_amdgcn_mfma_f32_16x16x32_bf16(krow[g],     qf0, acc, 0, 0, 0);
            acc = __builtin_amdgcn_mfma_f32_16x16x32_bf16(krow[4 + g], qf1, acc, 0, 0, 0);
            s[jj] = acc;
        }
        // ---- online softmax (per-lane column i)
        float pmax = -__builtin_inff();
        #pragma unroll
        for (int jj = 0; jj < 4; ++jj)
            #pragma unroll
            for (int e = 0; e < 4; ++e)
                pmax = fmaxf(pmax, s[jj][e]);
        pmax = fmaxf(pmax, __shfl_xor(pmax, 16));
        pmax = fmaxf(pmax, __shfl_xor(pmax, 32));
        float m_new = fmaxf(m_run, pmax);
        float alpha = __expf(m_run - m_new);   // first iter: exp(-inf)=0
        m_run = m_new;

        float p[16];
        float ls = 0.f;
        #pragma unroll
        for (int jj = 0; jj < 4; ++jj)
            #pragma unroll
            for (int e = 0; e < 4; ++e) {
                float pv = __expf(s[jj][e] - m_new);
                p[jj * 4 + e] = pv;
                ls += pv;
            }
        l_run = l_run * alpha + ls;
        #pragma unroll
        for (int cc = 0; cc < 4; ++cc)
            #pragma unroll
            for (int e = 0; e < 4; ++e)
                o_acc[cc][e] *= alpha;

        // ---- P fragments: slot s holds j = 4g+(s&3)+16*(s>>2) == p[s] / p[8+s]
        union U8 { bf16x8 v; short s[8]; };
        U8 pf0, pf1;
        #pragma unroll
        for (int e = 0; e < 8; ++e) {
            pf0.s[e] = f2bf(p[e]);
            pf1.s[e] = f2bf(p[8 + e]);
        }
        // ---- PV: O^T[c][i] accumulate
        #pragma unroll
        for (int cc = 0; cc < 4; ++cc) {
            const short* vrow = vb + (size_t)(cc * 16 + r) * NS + j0;
            union UV { bf16x8 v; bf16x4 h[2]; };
            UV vf;
            vf.h[0] = *(const bf16x4*)(vrow + 4 * g);
            vf.h[1] = *(const bf16x4*)(vrow + 4 * g + 16);
            o_acc[cc] = __builtin_amdgcn_mfma_f32_16x16x32_bf16(vf.v, pf0.v, o_acc[cc], 0, 0, 0);
            vf.h[0] = *(const bf16x4*)(vrow + 32 + 4 * g);
            vf.h[1] = *(const bf16x4*)(vrow + 32 + 4 * g + 16);
            o_acc[cc] = __builtin_amdgcn_mfma_f32_16x16x32_bf16(vf.v, pf1.v, o_acc[cc], 0, 0, 0);
        }
    }
    // ---- finalize: total l over the 4 disjoint lane-group partials
    float lt = l_run + __shfl_xor(l_run, 16);
    lt += __shfl_xor(lt, 32);
    float inv = 1.f / lt;
    float* hb = h + (size_t)b * NC * NS;
    #pragma unroll
    for (int cc = 0; cc < 4; ++cc)
        #pragma unroll
        for (int e = 0; e < 4; ++e)
            hb[(size_t)(cc * 16 + g * 4 + e) * NS + (i0 + r)] = o_acc[cc][e] * inv;
}

// ---------------------------------------------------------------------------
// Kernel 3a: output projection + residual. y = x + Wp*h + bp   (all f32)
// ---------------------------------------------------------------------------
__global__ __launch_bounds__(256) void out_proj(
    const float* __restrict__ x, const float* __restrict__ Wp,
    const float* __restrict__ bp, const float* __restrict__ h,
    float* __restrict__ y)
{
    int t  = threadIdx.x;
    int nl = t & 63;
    int og = __builtin_amdgcn_readfirstlane(t >> 6);
    int pos = blockIdx.x * 64 + nl;
    int b = pos >> 12;
    int n = pos & (NS - 1);

    float acc[16];
    #pragma unroll
    for (int o = 0; o < 16; ++o) acc[o] = bp[og * 16 + o];
    const float* hb = h + (size_t)b * NC * NS + n;
    #pragma unroll 4
    for (int c = 0; c < NC; ++c) {
        float hv = hb[(size_t)c * NS];
        #pragma unroll
        for (int o = 0; o < 16; ++o)
            acc[o] = fmaf(Wp[(og * 16 + o) * NC + c], hv, acc[o]);
    }
    const float* xb = x + (size_t)b * NC * NS + n;
    float* yb = y + (size_t)b * NC * NS + n;
    #pragma unroll
    for (int o = 0; o < 16; ++o)
        yb[(size_t)(og * 16 + o) * NS] = acc[o] + xb[(size_t)(og * 16 + o) * NS];
}

// ---------------------------------------------------------------------------
// Kernel 3b: GroupNorm(32 groups of 2 channels) + affine + Swish.
// One block per (b, group): 2 x 4096 elements, held in registers (single pass).
// ---------------------------------------------------------------------------
__global__ __launch_bounds__(256) void groupnorm_swish(
    const float* __restrict__ y, const float* __restrict__ gamma,
    const float* __restrict__ beta, float* __restrict__ out)
{
    int t  = threadIdx.x;
    int bg = blockIdx.x;              // 0..63
    int b  = bg >> 5;
    int gr = bg & 31;
    size_t base = ((size_t)b * NC + gr * 2) * NS;

    float vals[32];
    float s = 0.f, s2 = 0.f;
    #pragma unroll
    for (int i = 0; i < 32; ++i) {
        float v = y[base + t + 256 * i];
        vals[i] = v;
        s += v;
        s2 += v * v;
    }
    #pragma unroll
    for (int off = 32; off; off >>= 1) {
        s  += __shfl_xor(s, off);
        s2 += __shfl_xor(s2, off);
    }
    __shared__ float ls[4], ls2[4];
    int wid = t >> 6, lane = t & 63;
    if (lane == 0) { ls[wid] = s; ls2[wid] = s2; }
    __syncthreads();
    float st  = ls[0] + ls[1] + ls[2] + ls[3];
    float s2t = ls2[0] + ls2[1] + ls2[2] + ls2[3];
    float mean = st * (1.f / 8192.f);
    float var  = s2t * (1.f / 8192.f) - mean * mean;
    float rstd = rsqrtf(var + 1e-5f);
    float g0 = gamma[gr * 2], g1 = gamma[gr * 2 + 1];
    float b0 = beta[gr * 2],  b1 = beta[gr * 2 + 1];
    #pragma unroll
    for (int i = 0; i < 32; ++i) {
        int e = t + 256 * i;
        float gg = (e < NS) ? g0 : g1;
        float bb = (e < NS) ? b0 : b1;
        float yn = (vals[i] - mean) * rstd * gg + bb;
        float sw = yn / (1.f + __expf(-yn));   // yn * sigmoid(yn)
        out[base + e] = sw;
    }
}

// ---------------------------------------------------------------------------
extern "C" void kernel_launch(void* const* d_in, const int* in_sizes, int n_in,
                              void* d_out, int out_size, void* d_ws, size_t ws_size,
                              hipStream_t stream)
{
    const float* x     = (const float*)d_in[0];
    const float* Wq    = (const float*)d_in[1];
    const float* bq    = (const float*)d_in[2];
    const float* Wk    = (const float*)d_in[3];
    const float* bk    = (const float*)d_in[4];
    const float* Wv    = (const float*)d_in[5];
    const float* bv    = (const float*)d_in[6];
    const float* Wp    = (const float*)d_in[7];
    const float* bp    = (const float*)d_in[8];
    const float* gamma = (const float*)d_in[9];
    const float* beta  = (const float*)d_in[10];
    float* out = (float*)d_out;

    char* ws = (char*)d_ws;
    short* qT = (short*)(ws);                  // [B][N][C] bf16, 1 MB
    short* kT = (short*)(ws + (1u << 20));     // [B][N][C] bf16, 1 MB
    short* vN = (short*)(ws + (2u << 20));     // [B][C][N] bf16, 1 MB
    float* h  = (float*)(ws + (3u << 20));     // [B][C][N] f32,  2 MB
    float* y  = (float*)(ws + (5u << 20));     // [B][C][N] f32,  2 MB

    qkv_proj<<<128, 256, 0, stream>>>(x, Wq, bq, Wk, bk, Wv, bv, qT, kT, vN);
    flash_attn<<<128, 256, 0, stream>>>(qT, kT, vN, h);
    out_proj<<<128, 256, 0, stream>>>(x, Wp, bp, h, y);
    groupnorm_swish<<<64, 256, 0, stream>>>(y, gamma, beta, out);
}

// Round 3
// 179.289 us; speedup vs baseline: 1.6445x; 1.6445x over previous
//
#include <hip/hip_runtime.h>
#include <hip/hip_bf16.h>

// Problem constants (B,C,D,H,W = 2,64,16,16,16)
#define NB 2
#define NC 64
#define NS 4096   // D*H*W
#define GROUPS 32

typedef __attribute__((ext_vector_type(8))) short bf16x8;
typedef __attribute__((ext_vector_type(4))) short bf16x4;
typedef __attribute__((ext_vector_type(4))) float f32x4;
typedef __attribute__((ext_vector_type(4))) float float4v;

static __device__ __forceinline__ short f2bf(float f) {
    union { float f; unsigned u; } c; c.f = f;
    unsigned r = (c.u + 0x7FFFu + ((c.u >> 16) & 1u)) >> 16;  // RNE
    return (short)r;
}

// ---------------------------------------------------------------------------
// Kernel 1: QKV projection.  x:[B][C][N] f32 -> qT,kT:[B][N][C] bf16, vN:[B][C][N] bf16
// Grid (128, 12): y = matrix*4 + og-quarter. Block 256 = 64 pos x 4 waves.
// Each wave computes 4 output channels (wave-uniform W rows -> scalar loads).
// ---------------------------------------------------------------------------
__global__ __launch_bounds__(256) void qkv_proj(
    const float* __restrict__ x,
    const float* __restrict__ Wq, const float* __restrict__ bq,
    const float* __restrict__ Wk, const float* __restrict__ bk,
    const float* __restrict__ Wv, const float* __restrict__ bv,
    short* __restrict__ qT, short* __restrict__ kT, short* __restrict__ vN)
{
    int t  = threadIdx.x;
    int nl = t & 63;
    int wid = __builtin_amdgcn_readfirstlane(t >> 6);   // 0..3
    int m   = blockIdx.y >> 2;                          // 0=q 1=k 2=v
    int och = (blockIdx.y & 3) * 16 + wid * 4;          // 4 channels per wave
    int pos = blockIdx.x * 64 + nl;
    int b = pos >> 12;
    int n = pos & (NS - 1);

    const float* W    = (m == 0) ? Wq : (m == 1) ? Wk : Wv;
    const float* bias = (m == 0) ? bq : (m == 1) ? bk : bv;

    float acc[4];
    #pragma unroll
    for (int o = 0; o < 4; ++o) acc[o] = bias[och + o];

    const float* xb = x + (size_t)b * NC * NS + n;
    #pragma unroll 8
    for (int c = 0; c < NC; ++c) {
        float xv = xb[(size_t)c * NS];
        #pragma unroll
        for (int o = 0; o < 4; ++o)
            acc[o] = fmaf(W[(och + o) * NC + c], xv, acc[o]);
    }

    if (m < 2) {
        union U4 { bf16x4 v; short s[4]; } u;
        #pragma unroll
        for (int o = 0; o < 4; ++o) u.s[o] = f2bf(acc[o]);
        short* dst = (m == 0 ? qT : kT) + ((size_t)b * NS + n) * NC + och;
        *(bf16x4*)dst = u.v;
    } else {
        #pragma unroll
        for (int o = 0; o < 4; ++o)
            vN[((size_t)b * NC + och + o) * NS + n] = f2bf(acc[o]);
    }
}

// ---------------------------------------------------------------------------
// Kernel 2: flash attention, key-split across 8 waves of a block.
// Block = 512 thr (8 waves); grid = 512 (one 16-query tile per block).
// Wave w handles keys [w*512, (w+1)*512); partial (m, l, O) combined via LDS.
// S^T = mfma(A=K, B=Q): lane owns query col i=i0+(lane&15), rows j=4g+e (+16jj).
// PV:  O^T = mfma(A=V^T, B=P^T), P slot map == S^T C/D map -> zero-shuffle.
// ---------------------------------------------------------------------------
__global__ __launch_bounds__(512) void flash_attn(
    const short* __restrict__ qT, const short* __restrict__ kT,
    const short* __restrict__ vN, float* __restrict__ h)
{
    int t = threadIdx.x;
    int wid  = t >> 6;
    int lane = t & 63;
    int r = lane & 15;      // query index within tile (col of S^T)
    int g = lane >> 4;      // lane group
    int b  = blockIdx.x >> 8;
    int i0 = (blockIdx.x & 255) * 16;

    __shared__ float o_lds[8][64][17];
    __shared__ float m_lds[8][16];
    __shared__ float l_lds[8][16];

    const short* qb = qT + (size_t)b * NS * NC;
    const short* kb = kT + (size_t)b * NS * NC;
    const short* vb = vN + (size_t)b * NC * NS;

    // Q fragments (held all loop): B-operand, col = i0+r, k-slots c = 8g+s (+32)
    const bf16x8* qrow = (const bf16x8*)(qb + (size_t)(i0 + r) * NC);
    bf16x8 qf0 = qrow[g];
    bf16x8 qf1 = qrow[4 + g];

    f32x4 o_acc[4];
    #pragma unroll
    for (int cc = 0; cc < 4; ++cc) o_acc[cc] = (f32x4){0.f, 0.f, 0.f, 0.f};
    float m_run = -__builtin_inff();
    float l_run = 0.f;

    int jbeg = wid * (NS / 8);
    int jend = jbeg + (NS / 8);
    for (int j0 = jbeg; j0 < jend; j0 += 64) {
        // ---- S^T tiles: 4 j-chunks of 16 rows
        f32x4 s[4];
        #pragma unroll
        for (int jj = 0; jj < 4; ++jj) {
            const bf16x8* krow = (const bf16x8*)(kb + (size_t)(j0 + jj * 16 + r) * NC);
            f32x4 acc = (f32x4){0.f, 0.f, 0.f, 0.f};
            acc = __builtin_amdgcn_mfma_f32_16x16x32_bf16(krow[g],     qf0, acc, 0, 0, 0);
            acc = __builtin_amdgcn_mfma_f32_16x16x32_bf16(krow[4 + g], qf1, acc, 0, 0, 0);
            s[jj] = acc;
        }
        // ---- online softmax (per-lane column i)
        float pmax = -__builtin_inff();
        #pragma unroll
        for (int jj = 0; jj < 4; ++jj)
            #pragma unroll
            for (int e = 0; e < 4; ++e)
                pmax = fmaxf(pmax, s[jj][e]);
        pmax = fmaxf(pmax, __shfl_xor(pmax, 16));
        pmax = fmaxf(pmax, __shfl_xor(pmax, 32));
        float m_new = fmaxf(m_run, pmax);
        float alpha = __expf(m_run - m_new);   // first iter: exp(-inf)=0
        m_run = m_new;

        float p[16];
        float ls = 0.f;
        #pragma unroll
        for (int jj = 0; jj < 4; ++jj)
            #pragma unroll
            for (int e = 0; e < 4; ++e) {
                float pv = __expf(s[jj][e] - m_new);
                p[jj * 4 + e] = pv;
                ls += pv;
            }
        l_run = l_run * alpha + ls;
        #pragma unroll
        for (int cc = 0; cc < 4; ++cc)
            #pragma unroll
            for (int e = 0; e < 4; ++e)
                o_acc[cc][e] *= alpha;

        // ---- P fragments: slot s holds j = 4g+(s&3)+16*(s>>2) == p[s] / p[8+s]
        union U8 { bf16x8 v; short s[8]; };
        U8 pf0, pf1;
        #pragma unroll
        for (int e = 0; e < 8; ++e) {
            pf0.s[e] = f2bf(p[e]);
            pf1.s[e] = f2bf(p[8 + e]);
        }
        // ---- PV: O^T[c][i] accumulate
        #pragma unroll
        for (int cc = 0; cc < 4; ++cc) {
            const short* vrow = vb + (size_t)(cc * 16 + r) * NS + j0;
            union UV { bf16x8 v; bf16x4 h[2]; };
            UV vf;
            vf.h[0] = *(const bf16x4*)(vrow + 4 * g);
            vf.h[1] = *(const bf16x4*)(vrow + 4 * g + 16);
            o_acc[cc] = __builtin_amdgcn_mfma_f32_16x16x32_bf16(vf.v, pf0.v, o_acc[cc], 0, 0, 0);
            vf.h[0] = *(const bf16x4*)(vrow + 32 + 4 * g);
            vf.h[1] = *(const bf16x4*)(vrow + 32 + 4 * g + 16);
            o_acc[cc] = __builtin_amdgcn_mfma_f32_16x16x32_bf16(vf.v, pf1.v, o_acc[cc], 0, 0, 0);
        }
    }

    // ---- per-wave l total over the 4 disjoint lane-group partials
    float lt = l_run + __shfl_xor(l_run, 16);
    lt += __shfl_xor(lt, 32);

    // ---- write wave partials to LDS (o unnormalized; m,l per query r)
    #pragma unroll
    for (int cc = 0; cc < 4; ++cc)
        #pragma unroll
        for (int e = 0; e < 4; ++e)
            o_lds[wid][cc * 16 + g * 4 + e][r] = o_acc[cc][e];
    if (lane < 16) {
        m_lds[wid][r] = m_run;
        l_lds[wid][r] = lt;
    }
    __syncthreads();

    // ---- combine 8 wave-partials; 1024 (c,r) entries over 512 threads
    float* hb = h + (size_t)b * NC * NS;
    #pragma unroll
    for (int half = 0; half < 2; ++half) {
        int idx = t + half * 512;
        int c = idx >> 4;
        int rr = idx & 15;
        float M = m_lds[0][rr];
        #pragma unroll
        for (int w = 1; w < 8; ++w) M = fmaxf(M, m_lds[w][rr]);
        float L = 0.f, O = 0.f;
        #pragma unroll
        for (int w = 0; w < 8; ++w) {
            float a = __expf(m_lds[w][rr] - M);
            L += a * l_lds[w][rr];
            O += a * o_lds[w][c][rr];
        }
        hb[(size_t)c * NS + i0 + rr] = O / L;
    }
}

// ---------------------------------------------------------------------------
// Kernel 3a: output projection + residual. y = x + Wp*h + bp   (all f32)
// Grid (128, 4); block 256 = 64 pos x 4 waves; each wave does 4 out-channels.
// ---------------------------------------------------------------------------
__global__ __launch_bounds__(256) void out_proj(
    const float* __restrict__ x, const float* __restrict__ Wp,
    const float* __restrict__ bp, const float* __restrict__ h,
    float* __restrict__ y)
{
    int t  = threadIdx.x;
    int nl = t & 63;
    int wid = __builtin_amdgcn_readfirstlane(t >> 6);
    int och = blockIdx.y * 16 + wid * 4;
    int pos = blockIdx.x * 64 + nl;
    int b = pos >> 12;
    int n = pos & (NS - 1);

    float acc[4];
    #pragma unroll
    for (int o = 0; o < 4; ++o) acc[o] = bp[och + o];
    const float* hb = h + (size_t)b * NC * NS + n;
    #pragma unroll 8
    for (int c = 0; c < NC; ++c) {
        float hv = hb[(size_t)c * NS];
        #pragma unroll
        for (int o = 0; o < 4; ++o)
            acc[o] = fmaf(Wp[(och + o) * NC + c], hv, acc[o]);
    }
    const float* xb = x + (size_t)b * NC * NS + n;
    float* yb = y + (size_t)b * NC * NS + n;
    #pragma unroll
    for (int o = 0; o < 4; ++o)
        yb[(size_t)(och + o) * NS] = acc[o] + xb[(size_t)(och + o) * NS];
}

// ---------------------------------------------------------------------------
// Kernel 3b: GroupNorm(32 groups of 2 channels) + affine + Swish.
// One block of 1024 thr per (b, group): 8192 elems, 8 per thread (2x float4).
// ---------------------------------------------------------------------------
__global__ __launch_bounds__(1024) void groupnorm_swish(
    const float* __restrict__ y, const float* __restrict__ gamma,
    const float* __restrict__ beta, float* __restrict__ out)
{
    int t  = threadIdx.x;
    int bg = blockIdx.x;              // 0..63
    int b  = bg >> 5;
    int gr = bg & 31;
    size_t base = ((size_t)b * NC + gr * 2) * NS;

    float4v v0 = *(const float4v*)(y + base + t * 8);
    float4v v1 = *(const float4v*)(y + base + t * 8 + 4);
    float s = 0.f, s2 = 0.f;
    #pragma unroll
    for (int i = 0; i < 4; ++i) {
        s += v0[i] + v1[i];
        s2 += v0[i] * v0[i] + v1[i] * v1[i];
    }
    #pragma unroll
    for (int off = 32; off; off >>= 1) {
        s  += __shfl_xor(s, off);
        s2 += __shfl_xor(s2, off);
    }
    __shared__ float ls[16], ls2[16];
    int wid = t >> 6, lane = t & 63;
    if (lane == 0) { ls[wid] = s; ls2[wid] = s2; }
    __syncthreads();
    float st = 0.f, s2t = 0.f;
    #pragma unroll
    for (int w = 0; w < 16; ++w) { st += ls[w]; s2t += ls2[w]; }
    float mean = st * (1.f / 8192.f);
    float var  = s2t * (1.f / 8192.f) - mean * mean;
    float rstd = rsqrtf(var + 1e-5f);
    // thread t<512 -> channel 2g (elems 0..4095), else channel 2g+1
    float gg = (t < 512) ? gamma[gr * 2] : gamma[gr * 2 + 1];
    float bb = (t < 512) ? beta[gr * 2]  : beta[gr * 2 + 1];
    float4v o0, o1;
    #pragma unroll
    for (int i = 0; i < 4; ++i) {
        float yn = (v0[i] - mean) * rstd * gg + bb;
        o0[i] = yn / (1.f + __expf(-yn));
        float yn1 = (v1[i] - mean) * rstd * gg + bb;
        o1[i] = yn1 / (1.f + __expf(-yn1));
    }
    *(float4v*)(out + base + t * 8)     = o0;
    *(float4v*)(out + base + t * 8 + 4) = o1;
}

// ---------------------------------------------------------------------------
extern "C" void kernel_launch(void* const* d_in, const int* in_sizes, int n_in,
                              void* d_out, int out_size, void* d_ws, size_t ws_size,
                              hipStream_t stream)
{
    const float* x     = (const float*)d_in[0];
    const float* Wq    = (const float*)d_in[1];
    const float* bq    = (const float*)d_in[2];
    const float* Wk    = (const float*)d_in[3];
    const float* bk    = (const float*)d_in[4];
    const float* Wv    = (const float*)d_in[5];
    const float* bv    = (const float*)d_in[6];
    const float* Wp    = (const float*)d_in[7];
    const float* bp    = (const float*)d_in[8];
    const float* gamma = (const float*)d_in[9];
    const float* beta  = (const float*)d_in[10];
    float* out = (float*)d_out;

    char* ws = (char*)d_ws;
    short* qT = (short*)(ws);                  // [B][N][C] bf16, 1 MB
    short* kT = (short*)(ws + (1u << 20));     // [B][N][C] bf16, 1 MB
    short* vN = (short*)(ws + (2u << 20));     // [B][C][N] bf16, 1 MB
    float* h  = (float*)(ws + (3u << 20));     // [B][C][N] f32,  2 MB
    float* y  = (float*)(ws + (5u << 20));     // [B][C][N] f32,  2 MB

    qkv_proj<<<dim3(128, 12), 256, 0, stream>>>(x, Wq, bq, Wk, bk, Wv, bv, qT, kT, vN);
    flash_attn<<<512, 512, 0, stream>>>(qT, kT, vN, h);
    out_proj<<<dim3(128, 4), 256, 0, stream>>>(x, Wp, bp, h, y);
    groupnorm_swish<<<64, 1024, 0, stream>>>(y, gamma, beta, out);
}